// Round 4
// baseline (222.052 us; speedup 1.0000x reference)
//
#include <hip/hip_runtime.h>
#include <cstdint>

typedef __bf16 bf16x8 __attribute__((ext_vector_type(8)));
typedef float  f32x4  __attribute__((ext_vector_type(4)));

#define LOG2E 1.4426950408889634f

// split 8 f32 into hi/lo bf16 fragments (hi+lo ~ 16-bit mantissa)
__device__ __forceinline__ void split8(const float* v, bf16x8& hi, bf16x8& lo) {
    union { bf16x8 v; __bf16 e[8]; } h, l;
    #pragma unroll
    for (int j = 0; j < 8; j++) {
        __bf16 hb = (__bf16)v[j];
        float  r  = v[j] - (float)hb;
        h.e[j] = hb; l.e[j] = (__bf16)r;
    }
    hi = h.v; lo = l.v;
}
__device__ __forceinline__ bf16x8 cvt8(const float* v) {
    union { bf16x8 v; __bf16 e[8]; } u;
    #pragma unroll
    for (int j = 0; j < 8; j++) u.e[j] = (__bf16)v[j];
    return u.v;
}
__device__ __forceinline__ void splitstore(unsigned short* ph, unsigned short* pl, float v) {
    __bf16 hb = (__bf16)v;
    float  r  = v - (float)hb;
    __bf16 lb = (__bf16)r;
    unsigned short hu, lu;
    __builtin_memcpy(&hu, &hb, 2); __builtin_memcpy(&lu, &lb, 2);
    *ph = hu; *pl = lu;
}
__device__ __forceinline__ unsigned short f2bfh(float v) {
    __bf16 hb = (__bf16)v; unsigned short hu;
    __builtin_memcpy(&hu, &hb, 2); return hu;
}

// ---------------- Kzero: zero the atomic-accumulation region (fallback) -------
__global__ __launch_bounds__(256)
void kzero(float4* __restrict__ p) {
    p[blockIdx.x * 256 + threadIdx.x] = float4{0.f, 0.f, 0.f, 0.f};
}

// ---------------- Kpre: ballot bitpack (blocks 0..8191) + weight split --------
__global__ __launch_bounds__(256)
void kpre(const int* __restrict__ adj, unsigned long long* __restrict__ bm64,
          const float* __restrict__ w1, const float* __restrict__ w2,
          unsigned short* __restrict__ w1h, unsigned short* __restrict__ w1l,
          unsigned short* __restrict__ w2h, unsigned short* __restrict__ w2l) {
    int bx = blockIdx.x, tid = threadIdx.x;
    if (bx < 8192) {
        int row = bx >> 1, jbase = (bx & 1) * 2048;
        int wave = tid >> 6, lane = tid & 63;
        const int* base = adj + (size_t)row * 4096 + jbase + wave * 512;
        unsigned long long* bmw = bm64 + row * 64 + (jbase >> 6) + wave * 8;
        #pragma unroll
        for (int it = 0; it < 8; it++) {
            int v = base[it * 64 + lane];
            unsigned long long mask = __ballot(v != 0);
            if (lane == 0) bmw[it] = mask;
        }
        return;
    }
    // weight split role: 68 blocks x 256 thr x 4 = 69632 (w1 65536 + w2 4096)
    int e = ((bx - 8192) * 256 + tid) * 4;
    const float* src; unsigned short *dh, *dl;
    if (e < 65536) { src = w1 + e; dh = w1h + e; dl = w1l + e; }
    else { int e2 = e - 65536; src = w2 + e2; dh = w2h + e2; dl = w2l + e2; }
    #pragma unroll
    for (int j = 0; j < 4; j++) splitstore(dh + j, dl + j, src[j]);
}

// ---------------- K1: H1T[c][i] = (x @ W1^T)[i][c] bf16-hi, + f1/f2 epilogue --
// fvals stored pre-scaled by log2(e) so attention can use v_exp_f32 (2^x) raw.
__global__ __launch_bounds__(256)
void k1_gemm(const float* __restrict__ x,
             const unsigned short* __restrict__ w1h,
             const unsigned short* __restrict__ w1l,
             const float* __restrict__ a11, const float* __restrict__ a21,
             unsigned short* __restrict__ h1t_hi, float* __restrict__ fvals) {
    int tid = threadIdx.x, wave = tid >> 6, lane = tid & 63;
    int q = lane >> 4, m = lane & 15;
    int i0 = blockIdx.x * 16;
    int c0 = wave * 64;                     // wave == head
    f32x4 acc[4] = {};
    #pragma unroll
    for (int k0 = 0; k0 < 256; k0 += 32) {
        bf16x8 ah, al;
        split8(x + (i0 + m) * 256 + k0 + q * 8, ah, al);
        #pragma unroll
        for (int ct = 0; ct < 4; ct++) {
            bf16x8 bh = *(const bf16x8*)(w1h + (c0 + ct * 16 + m) * 256 + k0 + q * 8);
            bf16x8 bl = *(const bf16x8*)(w1l + (c0 + ct * 16 + m) * 256 + k0 + q * 8);
            acc[ct] = __builtin_amdgcn_mfma_f32_16x16x32_bf16(ah, bh, acc[ct], 0, 0, 0);
            acc[ct] = __builtin_amdgcn_mfma_f32_16x16x32_bf16(al, bh, acc[ct], 0, 0, 0);
            acc[ct] = __builtin_amdgcn_mfma_f32_16x16x32_bf16(ah, bl, acc[ct], 0, 0, 0);
        }
    }
    float a1v[4], a2v[4];
    #pragma unroll
    for (int ct = 0; ct < 4; ct++) {
        a1v[ct] = a11[wave * 64 + ct * 16 + m];
        a2v[ct] = a21[wave * 64 + ct * 16 + m];
    }
    #pragma unroll
    for (int r = 0; r < 4; r++) {
        int i = i0 + q * 4 + r;
        float s1 = 0.f, s2 = 0.f;
        #pragma unroll
        for (int ct = 0; ct < 4; ct++) {
            int c = c0 + ct * 16 + m;
            h1t_hi[c * 4096 + i] = f2bfh(acc[ct][r]);
            s1 += acc[ct][r] * a1v[ct];
            s2 += acc[ct][r] * a2v[ct];
        }
        #pragma unroll
        for (int off = 1; off < 16; off <<= 1) {
            s1 += __shfl_xor(s1, off);
            s2 += __shfl_xor(s2, off);
        }
        if (m == 0) {
            fvals[wave * 4096 + i] = s1 * LOG2E;
            fvals[16384 + wave * 4096 + i] = s2 * LOG2E;
        }
    }
}

// ---------------- attention (64-row tiles, barrier-free main loop) ------------
// no-max-subtraction softmax (e bounded). fvals pre-scaled by log2e; p=2^e'.
// masks + f2 staged once in LDS (single barrier). B fragments loaded DIRECTLY
// from global per wave (h1t is L1/L2-resident; each tile consumed exactly once
// so LDS staging had no reuse — it only added per-iteration barriers + stalls).
// Software-pipelined bcur/bnxt registers hide one full iteration of latency.
// grid (64 i-tiles, heads, 4096/JLEN chunks), 4 waves x 16 rows, free-running.
template<int NCT, int JLEN, bool ATOM>
__global__ __launch_bounds__(256)
void attn_kernel(const unsigned char* __restrict__ bmb,
                 const float* __restrict__ f1_all,
                 const float* __restrict__ f2_all,
                 const unsigned short* __restrict__ BTh_all,
                 float* __restrict__ pacc,
                 float* __restrict__ zacc,
                 int pstride) {
    constexpr int S    = JLEN / 32;                 // mask u32 per row
    constexpr int ST   = (S % 8 == 0) ? S + 4 : S;  // bank-safe padded stride
    constexpr int PR   = S / 4;                     // mask uint4 per row
    constexpr int R    = 64;                        // i-rows per block
    constexpr int NU4  = R * PR;
    constexpr int CR   = NCT * 16;                  // BT rows (head cols)
    int tid = threadIdx.x, wave = tid >> 6, lane = tid & 63;
    int q = lane >> 4, m = lane & 15;
    int head = blockIdx.y;
    int i0 = blockIdx.x * R;
    int jstart = blockIdx.z * JLEN;

    if (!ATOM) {
        pacc += (size_t)blockIdx.z * (size_t)(4096 * pstride);
        zacc += (size_t)blockIdx.z * (size_t)((NCT == 4 ? 4 : 1) * 4096);
    }

    __shared__ unsigned int ldsbm[R * ST];
    __shared__ float ldsf2[JLEN];

    const unsigned short* BTh = BTh_all + (size_t)head * CR * 4096;
    const float* f1 = f1_all + head * 4096;
    const float* f2 = f2_all + head * 4096;

    // stage bitmask slice
    for (int c = tid; c < NU4; c += 256) {
        int row = c / PR, part = c % PR;
        uint4 v = *(const uint4*)(bmb + (size_t)(i0 + row) * 512 + (jstart >> 3) + part * 16);
        *(uint4*)&ldsbm[row * ST + part * 4] = v;
    }
    // stage f2 slice (already log2e-scaled)
    for (int c = tid; c < JLEN / 4; c += 256)
        *(float4*)&ldsf2[c * 4] = *(const float4*)(f2 + jstart + c * 4);
    __syncthreads();                               // the only barrier

    int col0 = head * CR;
    int r0 = wave * 16;
    float f1s0 = f1[i0 + r0 + m];

    f32x4 acc0[NCT] = {};
    float z0 = 0.f;

    // per-lane B row base: lane (q,m) reads BT[ct*16+m][j + q*8 .. +7]
    const unsigned short* bbase = BTh + (size_t)m * 4096 + jstart + q * 8;

    bf16x8 bcur[NCT], bnxt[NCT];
    #pragma unroll
    for (int ct = 0; ct < NCT; ct++)
        bcur[ct] = *(const bf16x8*)(bbase + (size_t)ct * 16 * 4096);

    constexpr int NIT = JLEN / 32;
    for (int it = 0; it < NIT; it++) {
        int jl = it * 32;
        if (it + 1 < NIT) {
            #pragma unroll
            for (int ct = 0; ct < NCT; ct++)
                bnxt[ct] = *(const bf16x8*)(bbase + (size_t)ct * 16 * 4096 + jl + 32);
        }
        unsigned int md0 = ldsbm[(r0 + m) * ST + (jl >> 5)];
        const float4* f2p = (const float4*)&ldsf2[jl + q * 8];
        float4 fa = f2p[0], fb = f2p[1];
        float fv[8] = {fa.x, fa.y, fa.z, fa.w, fb.x, fb.y, fb.z, fb.w};
        float pv0[8];
        #pragma unroll
        for (int jj = 0; jj < 8; jj++) {
            int bit = q * 8 + jj;
            float s0 = f1s0 + fv[jj];
            float e0 = fmaxf(s0, 0.01f * s0);            // leaky_relu (scaled)
            bool v0 = ((md0 >> bit) & 1u) && (s0 != 0.0f);
            float p0 = v0 ? __builtin_amdgcn_exp2f(e0) : 0.0f;
            z0 += p0; pv0[jj] = p0;
        }
        bf16x8 ah0 = cvt8(pv0);
        #pragma unroll
        for (int ct = 0; ct < NCT; ct++)
            acc0[ct] = __builtin_amdgcn_mfma_f32_16x16x32_bf16(ah0, bcur[ct], acc0[ct], 0, 0, 0);
        #pragma unroll
        for (int ct = 0; ct < NCT; ct++)
            bcur[ct] = bnxt[ct];
    }
    z0 += __shfl_xor(z0, 16); z0 += __shfl_xor(z0, 32);
    if (lane < 16) {
        if (ATOM) {
            atomicAdd(&zacc[head * 4096 + i0 + r0 + lane], z0);
        } else {
            zacc[head * 4096 + i0 + r0 + lane] = z0;
        }
    }
    #pragma unroll
    for (int ct = 0; ct < NCT; ct++)
        #pragma unroll
        for (int r = 0; r < 4; r++) {
            int col = col0 + ct * 16 + m;
            int rowA = i0 + r0 + q * 4 + r;
            if (ATOM) {
                atomicAdd(&pacc[rowA * pstride + col], acc0[ct][r]);
            } else {
                pacc[rowA * pstride + col] = acc0[ct][r];
            }
        }
}

// ---------------- Fin1c: helu = elu(sum p1 / sum z1), coalesced, hi/lo bf16 ---
__global__ __launch_bounds__(256)
void fin1c(const float* __restrict__ pp, const float* __restrict__ zp, int nj,
           unsigned short* __restrict__ hh, unsigned short* __restrict__ hl) {
    int row = blockIdx.x, col = threadIdx.x;
    float s = 0.f;
    for (int jc = 0; jc < nj; jc++) s += pp[(size_t)jc * (4096 * 256) + row * 256 + col];
    int head = col >> 6;
    float zz = 0.f;
    for (int jc = 0; jc < nj; jc++) zz += zp[jc * (4 * 4096) + head * 4096 + row];
    float v = s / zz;
    v = (v > 0.f) ? v : (__expf(v) - 1.0f);
    splitstore(&hh[row * 256 + col], &hl[row * 256 + col], v);
}

// ---------------- K3: h2 = h_elu @ W2^T (hi/lo), f1_2/f2_2, h2T bf16-hi -------
// fq stored pre-scaled by log2(e).
__global__ __launch_bounds__(256)
void k3_layer2(const unsigned short* __restrict__ helu_hi,
               const unsigned short* __restrict__ helu_lo,
               const unsigned short* __restrict__ w2h,
               const unsigned short* __restrict__ w2l,
               const float* __restrict__ a12,
               const float* __restrict__ a22,
               unsigned short* __restrict__ h2t_hi,
               float* __restrict__ fq) {
    int tid = threadIdx.x, wave = tid >> 6, lane = tid & 63;
    int q = lane >> 4, m = lane & 15;
    int i0 = (blockIdx.x * 4 + wave) * 16;
    f32x4 acc = {};
    #pragma unroll
    for (int k0 = 0; k0 < 256; k0 += 32) {
        bf16x8 ah = *(const bf16x8*)(helu_hi + (i0 + m) * 256 + k0 + q * 8);
        bf16x8 al = *(const bf16x8*)(helu_lo + (i0 + m) * 256 + k0 + q * 8);
        bf16x8 bh = *(const bf16x8*)(w2h + m * 256 + k0 + q * 8);
        bf16x8 bl = *(const bf16x8*)(w2l + m * 256 + k0 + q * 8);
        acc = __builtin_amdgcn_mfma_f32_16x16x32_bf16(ah, bh, acc, 0, 0, 0);
        acc = __builtin_amdgcn_mfma_f32_16x16x32_bf16(al, bh, acc, 0, 0, 0);
        acc = __builtin_amdgcn_mfma_f32_16x16x32_bf16(ah, bl, acc, 0, 0, 0);
    }
    float a1v = a12[m], a2v = a22[m];
    #pragma unroll
    for (int r = 0; r < 4; r++) {
        float v = acc[r];
        int i = i0 + q * 4 + r;
        h2t_hi[m * 4096 + i] = f2bfh(v);
        float s1 = v * a1v, s2 = v * a2v;
        #pragma unroll
        for (int off = 1; off < 16; off <<= 1) {
            s1 += __shfl_xor(s1, off);
            s2 += __shfl_xor(s2, off);
        }
        if (m == 0) { fq[i] = s1 * LOG2E; fq[4096 + i] = s2 * LOG2E; }
    }
}

// ---------------- Fin2: out = sum(p2)/sum(z2) (f32) ---------------------------
__global__ __launch_bounds__(256)
void fin2(const float* __restrict__ pp, const float* __restrict__ zp, int nj,
          float* __restrict__ out) {
    int idx = blockIdx.x * 256 + threadIdx.x;      // 65536
    float s = 0.f;
    for (int jc = 0; jc < nj; jc++) s += pp[jc * 65536 + idx];
    float zz = 0.f;
    for (int jc = 0; jc < nj; jc++) zz += zp[jc * 4096 + (idx >> 4)];
    out[idx] = s / zz;
}

extern "C" void kernel_launch(void* const* d_in, const int* in_sizes, int n_in,
                              void* d_out, int out_size, void* d_ws, size_t ws_size,
                              hipStream_t stream) {
    const float* x   = (const float*)d_in[0];
    const int*   adj = (const int*)d_in[1];
    const float* w1  = (const float*)d_in[2];
    const float* a11 = (const float*)d_in[3];
    const float* a21 = (const float*)d_in[4];
    const float* w2  = (const float*)d_in[5];
    const float* a12 = (const float*)d_in[6];
    const float* a22 = (const float*)d_in[7];
    float* out = (float*)d_out;

    uint8_t* w = (uint8_t*)d_ws;
    unsigned long long* bm  = (unsigned long long*)(w);                       // 2 MB
    unsigned short* h1t_hi  = (unsigned short*)(w + (2u << 20));              // 2 MB
    unsigned short* h2t_hi  = (unsigned short*)(w + (4u << 20));              // 128 KB
    float*          fvals   = (float*)(w + (4u << 20) + (128u << 10));        // 128 KB
    float*          fq      = (float*)(w + (4u << 20) + (256u << 10));        // 32 KB
    unsigned short* w1h     = (unsigned short*)(w + (4u << 20) + (288u << 10)); // 128 KB
    unsigned short* w1l     = (unsigned short*)(w + (4u << 20) + (416u << 10)); // 128 KB
    unsigned short* w2h     = (unsigned short*)(w + (4u << 20) + (544u << 10)); // 8 KB
    unsigned short* w2l     = (unsigned short*)(w + (4u << 20) + (552u << 10)); // 8 KB
    unsigned short* helu_hi = (unsigned short*)(w + (4u << 20) + (560u << 10)); // 2 MB
    unsigned short* helu_lo = (unsigned short*)(w + (4u << 20) + (2608u << 10)); // 2 MB

    bool big = ws_size >= ((size_t)48 << 20);
    float* p1 = (float*)(w + (9u << 20));
    float *z1, *p2, *z2;
    if (big) {
        z1 = p1 + (size_t)4 * 4096 * 256;       // p1: 4 x 4 MB = 16 MB
        p2 = z1 + 4 * 4 * 4096;                 // z1: 4 x 64 KB
        z2 = p2 + (size_t)16 * 4096 * 16;       // p2: 16 x 256 KB = 4 MB
    } else {
        z1 = p1 + 4096 * 256;                   // p1: 4 MB
        p2 = z1 + 4 * 4096;                     // z1: 64 KB
        z2 = p2 + 4096 * 16;                    // p2: 256 KB, z2: 16 KB
    }

    if (!big) kzero<<<1108, 256, 0, stream>>>((float4*)p1);
    kpre<<<8260, 256, 0, stream>>>(adj, bm, w1, w2, w1h, w1l, w2h, w2l);
    k1_gemm<<<256, 256, 0, stream>>>(x, w1h, w1l, a11, a21, h1t_hi, fvals);
    if (big)
        attn_kernel<4, 1024, false><<<dim3(64, 4, 4), 256, 0, stream>>>(
            (const unsigned char*)bm, fvals, fvals + 16384, h1t_hi, p1, z1, 256);
    else
        attn_kernel<4, 1024, true><<<dim3(64, 4, 4), 256, 0, stream>>>(
            (const unsigned char*)bm, fvals, fvals + 16384, h1t_hi, p1, z1, 256);
    fin1c<<<4096, 256, 0, stream>>>(p1, z1, big ? 4 : 1, helu_hi, helu_lo);
    k3_layer2<<<64, 256, 0, stream>>>(helu_hi, helu_lo, w2h, w2l, a12, a22,
                                      h2t_hi, fq);
    if (big)
        attn_kernel<1, 256, false><<<dim3(64, 1, 16), 256, 0, stream>>>(
            (const unsigned char*)bm, fq, fq + 4096, h2t_hi, p2, z2, 16);
    else
        attn_kernel<1, 256, true><<<dim3(64, 1, 16), 256, 0, stream>>>(
            (const unsigned char*)bm, fq, fq + 4096, h2t_hi, p2, z2, 16);
    fin2<<<256, 256, 0, stream>>>(p2, z2, big ? 16 : 1, out);
}

// Round 5
// 190.880 us; speedup vs baseline: 1.1633x; 1.1633x over previous
//
#include <hip/hip_runtime.h>
#include <cstdint>

typedef __bf16 bf16x8 __attribute__((ext_vector_type(8)));
typedef float  f32x4  __attribute__((ext_vector_type(4)));

#define LOG2E 1.4426950408889634f

// split 8 f32 into hi/lo bf16 fragments (hi+lo ~ 16-bit mantissa)
__device__ __forceinline__ void split8(const float* v, bf16x8& hi, bf16x8& lo) {
    union { bf16x8 v; __bf16 e[8]; } h, l;
    #pragma unroll
    for (int j = 0; j < 8; j++) {
        __bf16 hb = (__bf16)v[j];
        float  r  = v[j] - (float)hb;
        h.e[j] = hb; l.e[j] = (__bf16)r;
    }
    hi = h.v; lo = l.v;
}
__device__ __forceinline__ bf16x8 cvt8(const float* v) {
    union { bf16x8 v; __bf16 e[8]; } u;
    #pragma unroll
    for (int j = 0; j < 8; j++) u.e[j] = (__bf16)v[j];
    return u.v;
}
__device__ __forceinline__ void splitstore(unsigned short* ph, unsigned short* pl, float v) {
    __bf16 hb = (__bf16)v;
    float  r  = v - (float)hb;
    __bf16 lb = (__bf16)r;
    unsigned short hu, lu;
    __builtin_memcpy(&hu, &hb, 2); __builtin_memcpy(&lu, &lb, 2);
    *ph = hu; *pl = lu;
}
__device__ __forceinline__ unsigned short f2bfh(float v) {
    __bf16 hb = (__bf16)v; unsigned short hu;
    __builtin_memcpy(&hu, &hb, 2); return hu;
}

// ---------------- Kzero: zero the atomic-accumulation region (fallback) -------
__global__ __launch_bounds__(256)
void kzero(float4* __restrict__ p) {
    p[blockIdx.x * 256 + threadIdx.x] = float4{0.f, 0.f, 0.f, 0.f};
}

// ---------------- Kpre: ballot bitpack (blocks 0..8191) + weight split --------
__global__ __launch_bounds__(256)
void kpre(const int* __restrict__ adj, unsigned long long* __restrict__ bm64,
          const float* __restrict__ w1, const float* __restrict__ w2,
          unsigned short* __restrict__ w1h, unsigned short* __restrict__ w1l,
          unsigned short* __restrict__ w2h, unsigned short* __restrict__ w2l) {
    int bx = blockIdx.x, tid = threadIdx.x;
    if (bx < 8192) {
        int row = bx >> 1, jbase = (bx & 1) * 2048;
        int wave = tid >> 6, lane = tid & 63;
        const int* base = adj + (size_t)row * 4096 + jbase + wave * 512;
        unsigned long long* bmw = bm64 + row * 64 + (jbase >> 6) + wave * 8;
        #pragma unroll
        for (int it = 0; it < 8; it++) {
            int v = base[it * 64 + lane];
            unsigned long long mask = __ballot(v != 0);
            if (lane == 0) bmw[it] = mask;
        }
        return;
    }
    // weight split role: 68 blocks x 256 thr x 4 = 69632 (w1 65536 + w2 4096)
    int e = ((bx - 8192) * 256 + tid) * 4;
    const float* src; unsigned short *dh, *dl;
    if (e < 65536) { src = w1 + e; dh = w1h + e; dl = w1l + e; }
    else { int e2 = e - 65536; src = w2 + e2; dh = w2h + e2; dl = w2l + e2; }
    #pragma unroll
    for (int j = 0; j < 4; j++) splitstore(dh + j, dl + j, src[j]);
}

// ---------------- K1: H1T[c][i] = (x @ W1^T)[i][c] bf16-hi, + f1/f2 epilogue --
// fvals stored pre-scaled by log2(e) so attention can use v_exp_f32 (2^x) raw.
__global__ __launch_bounds__(256)
void k1_gemm(const float* __restrict__ x,
             const unsigned short* __restrict__ w1h,
             const unsigned short* __restrict__ w1l,
             const float* __restrict__ a11, const float* __restrict__ a21,
             unsigned short* __restrict__ h1t_hi, float* __restrict__ fvals) {
    int tid = threadIdx.x, wave = tid >> 6, lane = tid & 63;
    int q = lane >> 4, m = lane & 15;
    int i0 = blockIdx.x * 16;
    int c0 = wave * 64;                     // wave == head
    f32x4 acc[4] = {};
    #pragma unroll
    for (int k0 = 0; k0 < 256; k0 += 32) {
        bf16x8 ah, al;
        split8(x + (i0 + m) * 256 + k0 + q * 8, ah, al);
        #pragma unroll
        for (int ct = 0; ct < 4; ct++) {
            bf16x8 bh = *(const bf16x8*)(w1h + (c0 + ct * 16 + m) * 256 + k0 + q * 8);
            bf16x8 bl = *(const bf16x8*)(w1l + (c0 + ct * 16 + m) * 256 + k0 + q * 8);
            acc[ct] = __builtin_amdgcn_mfma_f32_16x16x32_bf16(ah, bh, acc[ct], 0, 0, 0);
            acc[ct] = __builtin_amdgcn_mfma_f32_16x16x32_bf16(al, bh, acc[ct], 0, 0, 0);
            acc[ct] = __builtin_amdgcn_mfma_f32_16x16x32_bf16(ah, bl, acc[ct], 0, 0, 0);
        }
    }
    float a1v[4], a2v[4];
    #pragma unroll
    for (int ct = 0; ct < 4; ct++) {
        a1v[ct] = a11[wave * 64 + ct * 16 + m];
        a2v[ct] = a21[wave * 64 + ct * 16 + m];
    }
    #pragma unroll
    for (int r = 0; r < 4; r++) {
        int i = i0 + q * 4 + r;
        float s1 = 0.f, s2 = 0.f;
        #pragma unroll
        for (int ct = 0; ct < 4; ct++) {
            int c = c0 + ct * 16 + m;
            h1t_hi[c * 4096 + i] = f2bfh(acc[ct][r]);
            s1 += acc[ct][r] * a1v[ct];
            s2 += acc[ct][r] * a2v[ct];
        }
        #pragma unroll
        for (int off = 1; off < 16; off <<= 1) {
            s1 += __shfl_xor(s1, off);
            s2 += __shfl_xor(s2, off);
        }
        if (m == 0) {
            fvals[wave * 4096 + i] = s1 * LOG2E;
            fvals[16384 + wave * 4096 + i] = s2 * LOG2E;
        }
    }
}

// ---------------- attention (64-row tiles, LDS-staged BT, 2-deep pipeline) ----
// no-max-subtraction softmax (e bounded). fvals pre-scaled by log2e; p=2^e'.
// BT staged through LDS (coalesced stage loads; direct per-lane global reads
// would be 16-line gathers — measured 67us in R4 vs <40us staged).
// 2-iteration-deep register prefetch (vA/vB alternating, explicit 2-unroll so
// no reg-copy forces vmcnt(0)): the global load for tile it+2 is issued at it,
// ds_written at it+1 -> a full iteration of slack, write never stalls on L2.
// grid (64 i-tiles, heads, 4096/JLEN chunks), 4 waves x 16 rows.
template<int NCT, int JLEN, bool ATOM>
__global__ __launch_bounds__(256)
void attn_kernel(const unsigned char* __restrict__ bmb,
                 const float* __restrict__ f1_all,
                 const float* __restrict__ f2_all,
                 const unsigned short* __restrict__ BTh_all,
                 float* __restrict__ pacc,
                 float* __restrict__ zacc,
                 int pstride) {
    constexpr int S    = JLEN / 32;                 // mask u32 per row
    constexpr int ST   = (S % 8 == 0) ? S + 4 : S;  // bank-safe padded stride
    constexpr int PR   = S / 4;                     // mask uint4 per row
    constexpr int R    = 64;                        // i-rows per block
    constexpr int NU4  = R * PR;
    constexpr int CR   = NCT * 16;                  // BT tile rows
    constexpr int TSTR = 40;                        // tile row stride (halfwords)
    constexpr int NIT  = JLEN / 32;                 // even for all configs used
    int tid = threadIdx.x, wave = tid >> 6, lane = tid & 63;
    int q = lane >> 4, m = lane & 15;
    int head = blockIdx.y;
    int i0 = blockIdx.x * R;
    int jstart = blockIdx.z * JLEN;

    if (!ATOM) {
        pacc += (size_t)blockIdx.z * (size_t)(4096 * pstride);
        zacc += (size_t)blockIdx.z * (size_t)((NCT == 4 ? 4 : 1) * 4096);
    }

    __shared__ unsigned int ldsbm[R * ST];
    __shared__ unsigned short ldsbt[2][CR * TSTR];
    __shared__ float ldsf2[JLEN];

    const unsigned short* BTh = BTh_all + (size_t)head * CR * 4096;
    const float* f1 = f1_all + head * 4096;
    const float* f2 = f2_all + head * 4096;

    // stage bitmask slice
    for (int c = tid; c < NU4; c += 256) {
        int row = c / PR, part = c % PR;
        uint4 v = *(const uint4*)(bmb + (size_t)(i0 + row) * 512 + (jstart >> 3) + part * 16);
        *(uint4*)&ldsbm[row * ST + part * 4] = v;
    }
    // stage f2 slice (already log2e-scaled)
    for (int c = tid; c < JLEN / 4; c += 256)
        *(float4*)&ldsf2[c * 4] = *(const float4*)(f2 + jstart + c * 4);

    // BT staging roles: thread sc=tid/4 handles row sc, quarter sp=tid&3
    int sc = tid >> 2, sp = tid & 3;
    bool stager = tid < CR * 4;
    const unsigned short* sbase = BTh + (size_t)sc * 4096 + jstart + sp * 8;
    unsigned short* swr = &ldsbt[0][0] + sc * TSTR + sp * 8;

    uint4 vA, vB;
    if (stager) {
        uint4 v0 = *(const uint4*)(sbase);          // tile 0
        *(uint4*)(swr) = v0;                        // -> buf 0
        if (NIT > 1) vB = *(const uint4*)(sbase + 32);  // tile 1 held in vB
    }

    int col0 = head * CR;
    int r0 = wave * 16;
    float f1s0 = f1[i0 + r0 + m];

    f32x4 acc0[NCT] = {};
    float z0 = 0.f;

    constexpr int BUFO = CR * TSTR;                 // halfword offset buf0->buf1

    // body(it, vpre <- prefetch tile it+2, vwr -> ds_write tile it+1)
    auto body = [&](int it, uint4& vpre, uint4& vwr) {
        __syncthreads();
        int jl = it * 32;
        if (stager && it + 2 < NIT)
            vpre = *(const uint4*)(sbase + jl + 64);
        unsigned int md0 = ldsbm[(r0 + m) * ST + it];
        const float4* f2p = (const float4*)&ldsf2[jl + q * 8];
        float4 fa = f2p[0], fb = f2p[1];
        float fv[8] = {fa.x, fa.y, fa.z, fa.w, fb.x, fb.y, fb.z, fb.w};
        float pv0[8];
        #pragma unroll
        for (int jj = 0; jj < 8; jj++) {
            int bit = q * 8 + jj;
            float s0 = f1s0 + fv[jj];
            float e0 = fmaxf(s0, 0.01f * s0);            // leaky_relu (scaled)
            bool v0 = ((md0 >> bit) & 1u) && (s0 != 0.0f);
            float p0 = v0 ? __builtin_amdgcn_exp2f(e0) : 0.0f;
            z0 += p0; pv0[jj] = p0;
        }
        bf16x8 ah0 = cvt8(pv0);
        int cur = it & 1;
        const unsigned short* rb = &ldsbt[0][0] + cur * BUFO;
        #pragma unroll
        for (int ct = 0; ct < NCT; ct++) {
            bf16x8 bh = *(const bf16x8*)(rb + (ct * 16 + m) * TSTR + q * 8);
            acc0[ct] = __builtin_amdgcn_mfma_f32_16x16x32_bf16(ah0, bh, acc0[ct], 0, 0, 0);
        }
        if (stager && it + 1 < NIT)
            *(uint4*)(swr + (1 - cur) * BUFO) = vwr;
    };

    for (int itp = 0; itp < NIT; itp += 2) {
        body(itp,     vA, vB);   // prefetch->vA (tile itp+2), write vB (tile itp+1)
        body(itp + 1, vB, vA);   // prefetch->vB (tile itp+3), write vA (tile itp+2)
    }

    z0 += __shfl_xor(z0, 16); z0 += __shfl_xor(z0, 32);
    if (lane < 16) {
        if (ATOM) {
            atomicAdd(&zacc[head * 4096 + i0 + r0 + lane], z0);
        } else {
            zacc[head * 4096 + i0 + r0 + lane] = z0;
        }
    }
    #pragma unroll
    for (int ct = 0; ct < NCT; ct++)
        #pragma unroll
        for (int r = 0; r < 4; r++) {
            int col = col0 + ct * 16 + m;
            int rowA = i0 + r0 + q * 4 + r;
            if (ATOM) {
                atomicAdd(&pacc[rowA * pstride + col], acc0[ct][r]);
            } else {
                pacc[rowA * pstride + col] = acc0[ct][r];
            }
        }
}

// ---------------- Fin1c: helu = elu(sum p1 / sum z1), coalesced, hi/lo bf16 ---
__global__ __launch_bounds__(256)
void fin1c(const float* __restrict__ pp, const float* __restrict__ zp, int nj,
           unsigned short* __restrict__ hh, unsigned short* __restrict__ hl) {
    int row = blockIdx.x, col = threadIdx.x;
    float s = 0.f;
    for (int jc = 0; jc < nj; jc++) s += pp[(size_t)jc * (4096 * 256) + row * 256 + col];
    int head = col >> 6;
    float zz = 0.f;
    for (int jc = 0; jc < nj; jc++) zz += zp[jc * (4 * 4096) + head * 4096 + row];
    float v = s / zz;
    v = (v > 0.f) ? v : (__expf(v) - 1.0f);
    splitstore(&hh[row * 256 + col], &hl[row * 256 + col], v);
}

// ---------------- K3: h2 = h_elu @ W2^T (hi/lo), f1_2/f2_2, h2T bf16-hi -------
// fq stored pre-scaled by log2(e).
__global__ __launch_bounds__(256)
void k3_layer2(const unsigned short* __restrict__ helu_hi,
               const unsigned short* __restrict__ helu_lo,
               const unsigned short* __restrict__ w2h,
               const unsigned short* __restrict__ w2l,
               const float* __restrict__ a12,
               const float* __restrict__ a22,
               unsigned short* __restrict__ h2t_hi,
               float* __restrict__ fq) {
    int tid = threadIdx.x, wave = tid >> 6, lane = tid & 63;
    int q = lane >> 4, m = lane & 15;
    int i0 = (blockIdx.x * 4 + wave) * 16;
    f32x4 acc = {};
    #pragma unroll
    for (int k0 = 0; k0 < 256; k0 += 32) {
        bf16x8 ah = *(const bf16x8*)(helu_hi + (i0 + m) * 256 + k0 + q * 8);
        bf16x8 al = *(const bf16x8*)(helu_lo + (i0 + m) * 256 + k0 + q * 8);
        bf16x8 bh = *(const bf16x8*)(w2h + m * 256 + k0 + q * 8);
        bf16x8 bl = *(const bf16x8*)(w2l + m * 256 + k0 + q * 8);
        acc = __builtin_amdgcn_mfma_f32_16x16x32_bf16(ah, bh, acc, 0, 0, 0);
        acc = __builtin_amdgcn_mfma_f32_16x16x32_bf16(al, bh, acc, 0, 0, 0);
        acc = __builtin_amdgcn_mfma_f32_16x16x32_bf16(ah, bl, acc, 0, 0, 0);
    }
    float a1v = a12[m], a2v = a22[m];
    #pragma unroll
    for (int r = 0; r < 4; r++) {
        float v = acc[r];
        int i = i0 + q * 4 + r;
        h2t_hi[m * 4096 + i] = f2bfh(v);
        float s1 = v * a1v, s2 = v * a2v;
        #pragma unroll
        for (int off = 1; off < 16; off <<= 1) {
            s1 += __shfl_xor(s1, off);
            s2 += __shfl_xor(s2, off);
        }
        if (m == 0) { fq[i] = s1 * LOG2E; fq[4096 + i] = s2 * LOG2E; }
    }
}

// ---------------- Fin2: out = sum(p2)/sum(z2) (f32) ---------------------------
__global__ __launch_bounds__(256)
void fin2(const float* __restrict__ pp, const float* __restrict__ zp, int nj,
          float* __restrict__ out) {
    int idx = blockIdx.x * 256 + threadIdx.x;      // 65536
    float s = 0.f;
    for (int jc = 0; jc < nj; jc++) s += pp[jc * 65536 + idx];
    float zz = 0.f;
    for (int jc = 0; jc < nj; jc++) zz += zp[jc * 4096 + (idx >> 4)];
    out[idx] = s / zz;
}

extern "C" void kernel_launch(void* const* d_in, const int* in_sizes, int n_in,
                              void* d_out, int out_size, void* d_ws, size_t ws_size,
                              hipStream_t stream) {
    const float* x   = (const float*)d_in[0];
    const int*   adj = (const int*)d_in[1];
    const float* w1  = (const float*)d_in[2];
    const float* a11 = (const float*)d_in[3];
    const float* a21 = (const float*)d_in[4];
    const float* w2  = (const float*)d_in[5];
    const float* a12 = (const float*)d_in[6];
    const float* a22 = (const float*)d_in[7];
    float* out = (float*)d_out;

    uint8_t* w = (uint8_t*)d_ws;
    unsigned long long* bm  = (unsigned long long*)(w);                       // 2 MB
    unsigned short* h1t_hi  = (unsigned short*)(w + (2u << 20));              // 2 MB
    unsigned short* h2t_hi  = (unsigned short*)(w + (4u << 20));              // 128 KB
    float*          fvals   = (float*)(w + (4u << 20) + (128u << 10));        // 128 KB
    float*          fq      = (float*)(w + (4u << 20) + (256u << 10));        // 32 KB
    unsigned short* w1h     = (unsigned short*)(w + (4u << 20) + (288u << 10)); // 128 KB
    unsigned short* w1l     = (unsigned short*)(w + (4u << 20) + (416u << 10)); // 128 KB
    unsigned short* w2h     = (unsigned short*)(w + (4u << 20) + (544u << 10)); // 8 KB
    unsigned short* w2l     = (unsigned short*)(w + (4u << 20) + (552u << 10)); // 8 KB
    unsigned short* helu_hi = (unsigned short*)(w + (4u << 20) + (560u << 10)); // 2 MB
    unsigned short* helu_lo = (unsigned short*)(w + (4u << 20) + (2608u << 10)); // 2 MB

    bool big = ws_size >= ((size_t)48 << 20);
    float* p1 = (float*)(w + (9u << 20));
    float *z1, *p2, *z2;
    if (big) {
        z1 = p1 + (size_t)4 * 4096 * 256;       // p1: 4 x 4 MB = 16 MB
        p2 = z1 + 4 * 4 * 4096;                 // z1: 4 x 64 KB
        z2 = p2 + (size_t)16 * 4096 * 16;       // p2: 16 x 256 KB = 4 MB
    } else {
        z1 = p1 + 4096 * 256;                   // p1: 4 MB
        p2 = z1 + 4 * 4096;                     // z1: 64 KB
        z2 = p2 + 4096 * 16;                    // p2: 256 KB, z2: 16 KB
    }

    if (!big) kzero<<<1108, 256, 0, stream>>>((float4*)p1);
    kpre<<<8260, 256, 0, stream>>>(adj, bm, w1, w2, w1h, w1l, w2h, w2l);
    k1_gemm<<<256, 256, 0, stream>>>(x, w1h, w1l, a11, a21, h1t_hi, fvals);
    if (big)
        attn_kernel<4, 1024, false><<<dim3(64, 4, 4), 256, 0, stream>>>(
            (const unsigned char*)bm, fvals, fvals + 16384, h1t_hi, p1, z1, 256);
    else
        attn_kernel<4, 1024, true><<<dim3(64, 4, 4), 256, 0, stream>>>(
            (const unsigned char*)bm, fvals, fvals + 16384, h1t_hi, p1, z1, 256);
    fin1c<<<4096, 256, 0, stream>>>(p1, z1, big ? 4 : 1, helu_hi, helu_lo);
    k3_layer2<<<64, 256, 0, stream>>>(helu_hi, helu_lo, w2h, w2l, a12, a22,
                                      h2t_hi, fq);
    if (big)
        attn_kernel<1, 256, false><<<dim3(64, 1, 16), 256, 0, stream>>>(
            (const unsigned char*)bm, fq, fq + 4096, h2t_hi, p2, z2, 16);
    else
        attn_kernel<1, 256, true><<<dim3(64, 1, 16), 256, 0, stream>>>(
            (const unsigned char*)bm, fq, fq + 4096, h2t_hi, p2, z2, 16);
    fin2<<<256, 256, 0, stream>>>(p2, z2, big ? 16 : 1, out);
}

// Round 6
// 182.908 us; speedup vs baseline: 1.2140x; 1.0436x over previous
//
#include <hip/hip_runtime.h>
#include <cstdint>

typedef __bf16 bf16x8 __attribute__((ext_vector_type(8)));
typedef float  f32x4  __attribute__((ext_vector_type(4)));

#define LOG2E 1.4426950408889634f
#define LGKM0 do { asm volatile("s_waitcnt lgkmcnt(0)" ::: "memory"); \
                   __builtin_amdgcn_sched_barrier(0); } while (0)

// split 8 f32 into hi/lo bf16 fragments (hi+lo ~ 16-bit mantissa)
__device__ __forceinline__ void split8(const float* v, bf16x8& hi, bf16x8& lo) {
    union { bf16x8 v; __bf16 e[8]; } h, l;
    #pragma unroll
    for (int j = 0; j < 8; j++) {
        __bf16 hb = (__bf16)v[j];
        float  r  = v[j] - (float)hb;
        h.e[j] = hb; l.e[j] = (__bf16)r;
    }
    hi = h.v; lo = l.v;
}
__device__ __forceinline__ bf16x8 cvt8(const float* v) {
    union { bf16x8 v; __bf16 e[8]; } u;
    #pragma unroll
    for (int j = 0; j < 8; j++) u.e[j] = (__bf16)v[j];
    return u.v;
}
__device__ __forceinline__ void splitstore(unsigned short* ph, unsigned short* pl, float v) {
    __bf16 hb = (__bf16)v;
    float  r  = v - (float)hb;
    __bf16 lb = (__bf16)r;
    unsigned short hu, lu;
    __builtin_memcpy(&hu, &hb, 2); __builtin_memcpy(&lu, &lb, 2);
    *ph = hu; *pl = lu;
}
__device__ __forceinline__ unsigned short f2bfh(float v) {
    __bf16 hb = (__bf16)v; unsigned short hu;
    __builtin_memcpy(&hu, &hb, 2); return hu;
}

// ---------------- Kzero: zero the atomic-accumulation region (fallback) -------
__global__ __launch_bounds__(256)
void kzero(float4* __restrict__ p) {
    p[blockIdx.x * 256 + threadIdx.x] = float4{0.f, 0.f, 0.f, 0.f};
}

// ---------------- Kpre2: merged k1-GEMM (blocks 0..255) + adj bitpack ---------
// k1 splits W1 f32->bf16 hi/lo IN-REGISTER (bit-identical to the old kpre
// splitstore + kpre-produced buffers), removing the kpre->k1 dependency so the
// 256 k1 blocks (dispatched first) hide completely under the 64MB adj read.
__global__ __launch_bounds__(256)
void kpre2(const int* __restrict__ adj, unsigned long long* __restrict__ bm64,
           const float* __restrict__ x, const float* __restrict__ w1,
           const float* __restrict__ a11, const float* __restrict__ a21,
           unsigned short* __restrict__ h1t_hi, float* __restrict__ fvals) {
    int bx = blockIdx.x, tid = threadIdx.x;
    if (bx < 256) {
        // ---- k1 role: H1T[c][i] = (x @ W1^T)[i][c] bf16-hi + f1/f2 epilogue
        int wave = tid >> 6, lane = tid & 63;
        int q = lane >> 4, m = lane & 15;
        int i0 = bx * 16;
        int c0 = wave * 64;                     // wave == head
        f32x4 acc[4] = {};
        #pragma unroll
        for (int k0 = 0; k0 < 256; k0 += 32) {
            bf16x8 ah, al;
            split8(x + (i0 + m) * 256 + k0 + q * 8, ah, al);
            #pragma unroll
            for (int ct = 0; ct < 4; ct++) {
                bf16x8 bh, bl;
                split8(w1 + (c0 + ct * 16 + m) * 256 + k0 + q * 8, bh, bl);
                acc[ct] = __builtin_amdgcn_mfma_f32_16x16x32_bf16(ah, bh, acc[ct], 0, 0, 0);
                acc[ct] = __builtin_amdgcn_mfma_f32_16x16x32_bf16(al, bh, acc[ct], 0, 0, 0);
                acc[ct] = __builtin_amdgcn_mfma_f32_16x16x32_bf16(ah, bl, acc[ct], 0, 0, 0);
            }
        }
        float a1v[4], a2v[4];
        #pragma unroll
        for (int ct = 0; ct < 4; ct++) {
            a1v[ct] = a11[wave * 64 + ct * 16 + m];
            a2v[ct] = a21[wave * 64 + ct * 16 + m];
        }
        #pragma unroll
        for (int r = 0; r < 4; r++) {
            int i = i0 + q * 4 + r;
            float s1 = 0.f, s2 = 0.f;
            #pragma unroll
            for (int ct = 0; ct < 4; ct++) {
                int c = c0 + ct * 16 + m;
                h1t_hi[c * 4096 + i] = f2bfh(acc[ct][r]);
                s1 += acc[ct][r] * a1v[ct];
                s2 += acc[ct][r] * a2v[ct];
            }
            #pragma unroll
            for (int off = 1; off < 16; off <<= 1) {
                s1 += __shfl_xor(s1, off);
                s2 += __shfl_xor(s2, off);
            }
            if (m == 0) {
                fvals[wave * 4096 + i] = s1 * LOG2E;
                fvals[16384 + wave * 4096 + i] = s2 * LOG2E;
            }
        }
        return;
    }
    // ---- adj bitpack role (8192 blocks)
    int bxa = bx - 256;
    int row = bxa >> 1, jbase = (bxa & 1) * 2048;
    int wave = tid >> 6, lane = tid & 63;
    const int* base = adj + (size_t)row * 4096 + jbase + wave * 512;
    unsigned long long* bmw = bm64 + row * 64 + (jbase >> 6) + wave * 8;
    #pragma unroll
    for (int it = 0; it < 8; it++) {
        int v = base[it * 64 + lane];
        unsigned long long mask = __ballot(v != 0);
        if (lane == 0) bmw[it] = mask;
    }
}

// ---------------- attention (64-row tiles, 64-j iters, RAW barriers) ----------
// no-max-subtraction softmax (e bounded). fvals pre-scaled by log2e; p=2^e'.
// BT staged through LDS (coalesced; direct per-lane reads = 16-line gathers,
// measured 67us in R4). Key change: raw s_barrier + explicit lgkmcnt(0) only —
// __syncthreads' implicit vmcnt(0) was draining the prefetch at every barrier,
// defeating the pipeline (R5 neutral). Global prefetch now genuinely spans 2
// iterations; compiler inserts the counted vmcnt before the ds_write.
// 64 j per iteration (2x32 subtiles) halves barrier count.
// Same op order as 32-j version -> bit-identical results.
template<int NCT, int JLEN, bool ATOM>
__global__ __launch_bounds__(256)
void attn_kernel(const unsigned char* __restrict__ bmb,
                 const float* __restrict__ f1_all,
                 const float* __restrict__ f2_all,
                 const unsigned short* __restrict__ BTh_all,
                 float* __restrict__ pacc,
                 float* __restrict__ zacc,
                 int pstride) {
    constexpr int S    = JLEN / 32;                 // mask u32 per row
    constexpr int ST   = (S % 8 == 0) ? S + 4 : S;  // bank-safe padded stride (even)
    constexpr int PR   = S / 4;                     // mask uint4 per row
    constexpr int R    = 64;                        // i-rows per block
    constexpr int NU4  = R * PR;
    constexpr int CR   = NCT * 16;                  // BT tile rows
    constexpr int TSTR = 72;                        // 64-j tile row stride (hw)
    constexpr int NIT  = JLEN / 64;                 // 64-j iterations (even, >=4)
    constexpr int BUFO = CR * TSTR;
    int tid = threadIdx.x, wave = tid >> 6, lane = tid & 63;
    int q = lane >> 4, m = lane & 15;
    int head = blockIdx.y;
    int i0 = blockIdx.x * R;
    int jstart = blockIdx.z * JLEN;

    if (!ATOM) {
        pacc += (size_t)blockIdx.z * (size_t)(4096 * pstride);
        zacc += (size_t)blockIdx.z * (size_t)((NCT == 4 ? 4 : 1) * 4096);
    }

    __shared__ unsigned int ldsbm[R * ST];
    __shared__ unsigned short ldsbt[2][BUFO];
    __shared__ float ldsf2[JLEN];

    const unsigned short* BTh = BTh_all + (size_t)head * CR * 4096;
    const float* f1 = f1_all + head * 4096;
    const float* f2 = f2_all + head * 4096;

    // stage bitmask slice
    for (int c = tid; c < NU4; c += 256) {
        int row = c / PR, part = c % PR;
        uint4 v = *(const uint4*)(bmb + (size_t)(i0 + row) * 512 + (jstart >> 3) + part * 16);
        *(uint4*)&ldsbm[row * ST + part * 4] = v;
    }
    // stage f2 slice (already log2e-scaled)
    for (int c = tid; c < JLEN / 4; c += 256)
        *(float4*)&ldsf2[c * 4] = *(const float4*)(f2 + jstart + c * 4);

    // BT staging: thread t stages row t>>2, cols (t&3)*8 + {0,32} of each tile
    int sc = tid >> 2, sp = tid & 3;
    bool stager = (NCT == 4) ? true : (tid < CR * 4);
    const unsigned short* sbase = BTh + (size_t)sc * 4096 + jstart + sp * 8;
    unsigned short* swr0 = &ldsbt[0][0] + sc * TSTR + sp * 8;

    uint4 vA0, vA1, vB0, vB1;
    if (stager) {
        uint4 t00 = *(const uint4*)(sbase);
        uint4 t01 = *(const uint4*)(sbase + 32);
        *(uint4*)(swr0) = t00;                      // tile 0 -> buf 0
        *(uint4*)(swr0 + 32) = t01;
        vB0 = *(const uint4*)(sbase + 64);          // tile 1 held in vB
        vB1 = *(const uint4*)(sbase + 96);
    }

    int col0 = head * CR;
    int r0 = wave * 16;
    float f1s0 = f1[i0 + r0 + m];

    f32x4 acc0[NCT] = {};
    float z0 = 0.f;
    int mrow = (r0 + m) * ST;

    auto compute = [&](int it, int cur) {
        int jl = it * 64;
        unsigned long long mw = *(const unsigned long long*)&ldsbm[mrow + 2 * it];
        const unsigned short* rb = &ldsbt[0][0] + cur * BUFO;
        #pragma unroll
        for (int js = 0; js < 2; js++) {
            unsigned int md0 = (js == 0) ? (unsigned int)mw : (unsigned int)(mw >> 32);
            const float4* f2p = (const float4*)&ldsf2[jl + js * 32 + q * 8];
            float4 fa = f2p[0], fb = f2p[1];
            float fv[8] = {fa.x, fa.y, fa.z, fa.w, fb.x, fb.y, fb.z, fb.w};
            float pv0[8];
            #pragma unroll
            for (int jj = 0; jj < 8; jj++) {
                int bit = q * 8 + jj;
                float s0 = f1s0 + fv[jj];
                float e0 = fmaxf(s0, 0.01f * s0);            // leaky_relu (scaled)
                bool v0 = ((md0 >> bit) & 1u) && (s0 != 0.0f);
                float p0 = v0 ? __builtin_amdgcn_exp2f(e0) : 0.0f;
                z0 += p0; pv0[jj] = p0;
            }
            bf16x8 ah0 = cvt8(pv0);
            #pragma unroll
            for (int ct = 0; ct < NCT; ct++) {
                bf16x8 bh = *(const bf16x8*)(rb + (ct * 16 + m) * TSTR + js * 32 + q * 8);
                acc0[ct] = __builtin_amdgcn_mfma_f32_16x16x32_bf16(ah0, bh, acc0[ct], 0, 0, 0);
            }
        }
    };

    LGKM0;                                           // publish prologue ds_writes
    for (int itp = 0; itp + 2 < NIT; itp += 2) {
        __builtin_amdgcn_s_barrier();
        if (stager) {                                // prefetch tile itp+2 -> vA
            vA0 = *(const uint4*)(sbase + (itp + 2) * 64);
            vA1 = *(const uint4*)(sbase + (itp + 2) * 64 + 32);
        }
        compute(itp, 0);
        if (stager) {                                // write tile itp+1 -> buf1
            *(uint4*)(swr0 + BUFO) = vB0;
            *(uint4*)(swr0 + BUFO + 32) = vB1;
        }
        LGKM0;
        __builtin_amdgcn_s_barrier();
        if (stager) {                                // prefetch tile itp+3 -> vB
            vB0 = *(const uint4*)(sbase + (itp + 3) * 64);
            vB1 = *(const uint4*)(sbase + (itp + 3) * 64 + 32);
        }
        compute(itp + 1, 1);
        if (stager) {                                // write tile itp+2 -> buf0
            *(uint4*)(swr0) = vA0;
            *(uint4*)(swr0 + 32) = vA1;
        }
        LGKM0;
    }
    __builtin_amdgcn_s_barrier();
    compute(NIT - 2, 0);
    if (stager) {                                    // write tile NIT-1 -> buf1
        *(uint4*)(swr0 + BUFO) = vB0;
        *(uint4*)(swr0 + BUFO + 32) = vB1;
    }
    LGKM0;
    __builtin_amdgcn_s_barrier();
    compute(NIT - 1, 1);

    z0 += __shfl_xor(z0, 16); z0 += __shfl_xor(z0, 32);
    if (lane < 16) {
        if (ATOM) {
            atomicAdd(&zacc[head * 4096 + i0 + r0 + lane], z0);
        } else {
            zacc[head * 4096 + i0 + r0 + lane] = z0;
        }
    }
    #pragma unroll
    for (int ct = 0; ct < NCT; ct++)
        #pragma unroll
        for (int r = 0; r < 4; r++) {
            int col = col0 + ct * 16 + m;
            int rowA = i0 + r0 + q * 4 + r;
            if (ATOM) {
                atomicAdd(&pacc[rowA * pstride + col], acc0[ct][r]);
            } else {
                pacc[rowA * pstride + col] = acc0[ct][r];
            }
        }
}

// ---------------- Fin1c: helu = elu(sum p1 / sum z1), coalesced, hi/lo bf16 ---
__global__ __launch_bounds__(256)
void fin1c(const float* __restrict__ pp, const float* __restrict__ zp, int nj,
           unsigned short* __restrict__ hh, unsigned short* __restrict__ hl) {
    int row = blockIdx.x, col = threadIdx.x;
    float s = 0.f;
    for (int jc = 0; jc < nj; jc++) s += pp[(size_t)jc * (4096 * 256) + row * 256 + col];
    int head = col >> 6;
    float zz = 0.f;
    for (int jc = 0; jc < nj; jc++) zz += zp[jc * (4 * 4096) + head * 4096 + row];
    float v = s / zz;
    v = (v > 0.f) ? v : (__expf(v) - 1.0f);
    splitstore(&hh[row * 256 + col], &hl[row * 256 + col], v);
}

// ---------------- K3: h2 = h_elu @ W2^T (in-register W2 split), fq ------------
// fq stored pre-scaled by log2(e).
__global__ __launch_bounds__(256)
void k3_layer2(const unsigned short* __restrict__ helu_hi,
               const unsigned short* __restrict__ helu_lo,
               const float* __restrict__ w2,
               const float* __restrict__ a12,
               const float* __restrict__ a22,
               unsigned short* __restrict__ h2t_hi,
               float* __restrict__ fq) {
    int tid = threadIdx.x, wave = tid >> 6, lane = tid & 63;
    int q = lane >> 4, m = lane & 15;
    int i0 = (blockIdx.x * 4 + wave) * 16;
    f32x4 acc = {};
    #pragma unroll
    for (int k0 = 0; k0 < 256; k0 += 32) {
        bf16x8 ah = *(const bf16x8*)(helu_hi + (i0 + m) * 256 + k0 + q * 8);
        bf16x8 al = *(const bf16x8*)(helu_lo + (i0 + m) * 256 + k0 + q * 8);
        bf16x8 bh, bl;
        split8(w2 + m * 256 + k0 + q * 8, bh, bl);
        acc = __builtin_amdgcn_mfma_f32_16x16x32_bf16(ah, bh, acc, 0, 0, 0);
        acc = __builtin_amdgcn_mfma_f32_16x16x32_bf16(al, bh, acc, 0, 0, 0);
        acc = __builtin_amdgcn_mfma_f32_16x16x32_bf16(ah, bl, acc, 0, 0, 0);
    }
    float a1v = a12[m], a2v = a22[m];
    #pragma unroll
    for (int r = 0; r < 4; r++) {
        float v = acc[r];
        int i = i0 + q * 4 + r;
        h2t_hi[m * 4096 + i] = f2bfh(v);
        float s1 = v * a1v, s2 = v * a2v;
        #pragma unroll
        for (int off = 1; off < 16; off <<= 1) {
            s1 += __shfl_xor(s1, off);
            s2 += __shfl_xor(s2, off);
        }
        if (m == 0) { fq[i] = s1 * LOG2E; fq[4096 + i] = s2 * LOG2E; }
    }
}

// ---------------- Fin2: out = sum(p2)/sum(z2) (f32) ---------------------------
__global__ __launch_bounds__(256)
void fin2(const float* __restrict__ pp, const float* __restrict__ zp, int nj,
          float* __restrict__ out) {
    int idx = blockIdx.x * 256 + threadIdx.x;      // 65536
    float s = 0.f;
    for (int jc = 0; jc < nj; jc++) s += pp[jc * 65536 + idx];
    float zz = 0.f;
    for (int jc = 0; jc < nj; jc++) zz += zp[jc * 4096 + (idx >> 4)];
    out[idx] = s / zz;
}

extern "C" void kernel_launch(void* const* d_in, const int* in_sizes, int n_in,
                              void* d_out, int out_size, void* d_ws, size_t ws_size,
                              hipStream_t stream) {
    const float* x   = (const float*)d_in[0];
    const int*   adj = (const int*)d_in[1];
    const float* w1  = (const float*)d_in[2];
    const float* a11 = (const float*)d_in[3];
    const float* a21 = (const float*)d_in[4];
    const float* w2  = (const float*)d_in[5];
    const float* a12 = (const float*)d_in[6];
    const float* a22 = (const float*)d_in[7];
    float* out = (float*)d_out;

    uint8_t* w = (uint8_t*)d_ws;
    unsigned long long* bm  = (unsigned long long*)(w);                       // 2 MB
    unsigned short* h1t_hi  = (unsigned short*)(w + (2u << 20));              // 2 MB
    unsigned short* h2t_hi  = (unsigned short*)(w + (4u << 20));              // 128 KB
    float*          fvals   = (float*)(w + (4u << 20) + (128u << 10));        // 128 KB
    float*          fq      = (float*)(w + (4u << 20) + (256u << 10));        // 32 KB
    unsigned short* helu_hi = (unsigned short*)(w + (4u << 20) + (560u << 10)); // 2 MB
    unsigned short* helu_lo = (unsigned short*)(w + (4u << 20) + (2608u << 10)); // 2 MB

    bool big = ws_size >= ((size_t)48 << 20);
    float* p1 = (float*)(w + (9u << 20));
    float *z1, *p2, *z2;
    if (big) {
        z1 = p1 + (size_t)4 * 4096 * 256;       // p1: 4 x 4 MB = 16 MB
        p2 = z1 + 4 * 4 * 4096;                 // z1: 4 x 64 KB
        z2 = p2 + (size_t)16 * 4096 * 16;       // p2: 16 x 256 KB = 4 MB
    } else {
        z1 = p1 + 4096 * 256;                   // p1: 4 MB
        p2 = z1 + 4 * 4096;                     // z1: 64 KB
        z2 = p2 + 4096 * 16;                    // p2: 256 KB, z2: 16 KB
    }

    if (!big) kzero<<<1108, 256, 0, stream>>>((float4*)p1);
    kpre2<<<8448, 256, 0, stream>>>(adj, bm, x, w1, a11, a21, h1t_hi, fvals);
    if (big)
        attn_kernel<4, 1024, false><<<dim3(64, 4, 4), 256, 0, stream>>>(
            (const unsigned char*)bm, fvals, fvals + 16384, h1t_hi, p1, z1, 256);
    else
        attn_kernel<4, 1024, true><<<dim3(64, 4, 4), 256, 0, stream>>>(
            (const unsigned char*)bm, fvals, fvals + 16384, h1t_hi, p1, z1, 256);
    fin1c<<<4096, 256, 0, stream>>>(p1, z1, big ? 4 : 1, helu_hi, helu_lo);
    k3_layer2<<<64, 256, 0, stream>>>(helu_hi, helu_lo, w2, a12, a22,
                                      h2t_hi, fq);
    if (big)
        attn_kernel<1, 256, false><<<dim3(64, 1, 16), 256, 0, stream>>>(
            (const unsigned char*)bm, fq, fq + 4096, h2t_hi, p2, z2, 16);
    else
        attn_kernel<1, 256, true><<<dim3(64, 1, 16), 256, 0, stream>>>(
            (const unsigned char*)bm, fq, fq + 4096, h2t_hi, p2, z2, 16);
    fin2<<<256, 256, 0, stream>>>(p2, z2, big ? 16 : 1, out);
}